// Round 1
// baseline (148.736 us; speedup 1.0000x reference)
//
#include <hip/hip_runtime.h>

// ---------- types ----------
typedef __attribute__((ext_vector_type(8))) short s16x8;   // 8 x bf16 (4 VGPR)
typedef __attribute__((ext_vector_type(4))) float f32x4;   // MFMA acc

#define B_SZ 64
#define T_SZ 2000
#define QD 1024
#define MD 512
#define AD 128
#define NF 32
#define KW 31

// ---------- helpers ----------
__device__ __forceinline__ unsigned short f2bf(float f) {
    unsigned int u = __float_as_uint(f);
    unsigned int r = (u + 0x7FFFu + ((u >> 16) & 1u)) >> 16;  // RNE
    return (unsigned short)r;
}
__device__ __forceinline__ unsigned int pack2bf(float a, float b) {
    return (unsigned int)f2bf(a) | ((unsigned int)f2bf(b) << 16);
}
__device__ __forceinline__ float fast_tanh(float x) {
    float ax = fabsf(x);
    float e = __expf(2.0f * ax);
    float r = 1.0f - 2.0f * __builtin_amdgcn_rcpf(e + 1.0f);
    return x < 0.0f ? -r : r;
}

// ---------- kernel A: pq + weight packing ----------
// blocks 0..63: pq[b][d] = tanh(ahs[b] . Wq[:,d])
// blocks 64..95: pack W_memory -> bf16 MFMA B-frag layout
//   WB[((n*16+s)*64+l)*8+j] = bf16( Wm[(s*32+8*(l>>4)+j)*128 + n*16+(l&15)] )
// block 96: pack W_loc similarly (K=32, single k-step)
__global__ __launch_bounds__(256) void prep_kernel(
    const float* __restrict__ ahs, const float* __restrict__ Wq,
    const float* __restrict__ Wm, const float* __restrict__ Wl,
    float* __restrict__ pq, unsigned short* __restrict__ WB,
    unsigned short* __restrict__ WL) {
    const int blk = blockIdx.x, tid = threadIdx.x;
    if (blk < 64) {
        __shared__ float q_sm[QD];
        ((float4*)q_sm)[tid] = ((const float4*)(ahs + blk * QD))[tid];
        __syncthreads();
        if (tid < AD) {
            float acc = 0.0f;
            for (int k = 0; k < QD; ++k) acc += q_sm[k] * Wq[k * AD + tid];
            pq[blk * AD + tid] = fast_tanh(acc);
        }
    } else if (blk < 96) {
        int cidx = (blk - 64) * 256 + tid;        // 0..8191 = (n,s,l)
        int n = cidx >> 10, s = (cidx >> 6) & 15, l = cidx & 63;
        int col = n * 16 + (l & 15);
        int krow = s * 32 + (l >> 4) * 8;
        float v[8];
        #pragma unroll
        for (int j = 0; j < 8; ++j) v[j] = Wm[(krow + j) * AD + col];
        uint4 pk;
        pk.x = pack2bf(v[0], v[1]); pk.y = pack2bf(v[2], v[3]);
        pk.z = pack2bf(v[4], v[5]); pk.w = pack2bf(v[6], v[7]);
        *(uint4*)(WB + cidx * 8) = pk;
    } else {
        for (int h = 0; h < 2; ++h) {
            int cidx = h * 256 + tid;             // 0..511 = (n,l)
            int n = cidx >> 6, l = cidx & 63;
            int col = n * 16 + (l & 15);
            int krow = (l >> 4) * 8;
            float v[8];
            #pragma unroll
            for (int j = 0; j < 8; ++j) v[j] = Wl[(krow + j) * AD + col];
            uint4 pk;
            pk.x = pack2bf(v[0], v[1]); pk.y = pack2bf(v[2], v[3]);
            pk.z = pack2bf(v[4], v[5]); pk.w = pack2bf(v[6], v[7]);
            *(uint4*)(WL + cidx * 8) = pk;
        }
    }
}

// ---------- kernel B: fused conv + pm + ploc + energies ----------
// grid (63, 64); block 256 (4 waves). t-tile = 32.
__global__ __launch_bounds__(256) void energy_kernel(
    const float* __restrict__ memory, const float* __restrict__ awcat,
    const float* __restrict__ Wconv, const float* __restrict__ Wv,
    const float* __restrict__ pq, const unsigned short* __restrict__ WB,
    const unsigned short* __restrict__ WL, float* __restrict__ energies) {
    const int tile = blockIdx.x;
    const int b = blockIdx.y;
    const int t0 = tile * 32;
    const int tid = threadIdx.x;

    __shared__ __align__(16) unsigned short Atile[32 * 512]; // bf16, XOR-swizzled
    __shared__ float aw_sm[2][64];
    __shared__ __align__(16) unsigned short conv_sm[32 * 40]; // row stride 40 bf16
    __shared__ float e_part[32][4];

    // awc slice: indices i=0..62 -> t = t0-15+i  (zero pad OOB)
    if (tid < 128) {
        int c = tid >> 6, i = tid & 63;
        float v = 0.0f;
        int tv = t0 - 15 + i;
        if (i < 63 && tv >= 0 && tv < T_SZ) v = awcat[(b * 2 + c) * T_SZ + tv];
        aw_sm[c][i] = v;
    }

    // stage memory tile -> bf16 LDS, swizzled: byte ^= (row&7)<<4
    {
        const float4* msrc = (const float4*)(memory + ((size_t)b * T_SZ + t0) * MD);
        #pragma unroll
        for (int it = 0; it < 8; ++it) {
            int cid = it * 256 + tid;          // 2048 chunks of 8 floats
            int r = cid >> 6, cc = cid & 63;
            float4 v0 = {0, 0, 0, 0}, v1 = {0, 0, 0, 0};
            if (t0 + r < T_SZ) {
                v0 = msrc[r * 128 + cc * 2];
                v1 = msrc[r * 128 + cc * 2 + 1];
            }
            uint4 pk;
            pk.x = pack2bf(v0.x, v0.y); pk.y = pack2bf(v0.z, v0.w);
            pk.z = pack2bf(v1.x, v1.y); pk.w = pack2bf(v1.z, v1.w);
            int off = (r * 1024 + cc * 16) ^ ((r & 7) << 4);
            *(uint4*)((char*)Atile + off) = pk;
        }
    }
    __syncthreads();

    // conv1d: thread = (f = tid&31, tq = tid>>5); 4 t's per thread
    {
        int f = tid & 31, tq = tid >> 5;
        float acc[4] = {0, 0, 0, 0};
        for (int k = 0; k < KW; ++k) {
            #pragma unroll
            for (int c = 0; c < 2; ++c) {
                float wv = Wconv[(k * 2 + c) * NF + f];
                #pragma unroll
                for (int tt = 0; tt < 4; ++tt)
                    acc[tt] += wv * aw_sm[c][tq + tt * 8 + k];
            }
        }
        #pragma unroll
        for (int tt = 0; tt < 4; ++tt)
            conv_sm[(tq + tt * 8) * 40 + f] = f2bf(acc[tt]);
    }
    __syncthreads();

    // MFMA phase
    const int w = tid >> 6, l = tid & 63;
    const int lr = l & 15, lg = l >> 4;
    const int d0 = (2 * w + 0) * 16 + lr;
    const int d1 = (2 * w + 1) * 16 + lr;
    const float pqv0 = pq[b * AD + d0], pqv1 = pq[b * AD + d1];
    const float wvv0 = Wv[d0], wvv1 = Wv[d1];

    f32x4 zero4 = {0, 0, 0, 0};
    f32x4 p00 = zero4, p01 = zero4, p10 = zero4, p11 = zero4;

    const s16x8* wbp = (const s16x8*)WB;
    const int swz = (lr & 7) << 4;
    const int abase0 = lr * 1024 + lg * 16;          // mtile 0 row byte base
    const int abase1 = (16 + lr) * 1024 + lg * 16;   // mtile 1

    #pragma unroll
    for (int s = 0; s < 16; ++s) {
        s16x8 a0 = *(const s16x8*)((const char*)Atile + ((abase0 + s * 64) ^ swz));
        s16x8 a1 = *(const s16x8*)((const char*)Atile + ((abase1 + s * 64) ^ swz));
        s16x8 b0 = wbp[((2 * w + 0) * 16 + s) * 64 + l];
        s16x8 b1 = wbp[((2 * w + 1) * 16 + s) * 64 + l];
        p00 = __builtin_amdgcn_mfma_f32_16x16x32_bf16(a0, b0, p00, 0, 0, 0);
        p01 = __builtin_amdgcn_mfma_f32_16x16x32_bf16(a0, b1, p01, 0, 0, 0);
        p10 = __builtin_amdgcn_mfma_f32_16x16x32_bf16(a1, b0, p10, 0, 0, 0);
        p11 = __builtin_amdgcn_mfma_f32_16x16x32_bf16(a1, b1, p11, 0, 0, 0);
    }

    // ploc MFMA (K=32, one step)
    s16x8 la0 = *(const s16x8*)((const char*)conv_sm + (lr * 80 + lg * 16));
    s16x8 la1 = *(const s16x8*)((const char*)conv_sm + ((16 + lr) * 80 + lg * 16));
    const s16x8* wlp = (const s16x8*)WL;
    s16x8 lb0 = wlp[(2 * w + 0) * 64 + l];
    s16x8 lb1 = wlp[(2 * w + 1) * 64 + l];
    f32x4 q00 = __builtin_amdgcn_mfma_f32_16x16x32_bf16(la0, lb0, zero4, 0, 0, 0);
    f32x4 q01 = __builtin_amdgcn_mfma_f32_16x16x32_bf16(la0, lb1, zero4, 0, 0, 0);
    f32x4 q10 = __builtin_amdgcn_mfma_f32_16x16x32_bf16(la1, lb0, zero4, 0, 0, 0);
    f32x4 q11 = __builtin_amdgcn_mfma_f32_16x16x32_bf16(la1, lb1, zero4, 0, 0, 0);

    // epilogue: e[t] partial = sum_d tanh(pq + tanh(ploc) + tanh(pm)) * Wv
    float vr[8];
    #pragma unroll
    for (int r = 0; r < 4; ++r) {
        vr[r]     = fast_tanh(pqv0 + fast_tanh(q00[r]) + fast_tanh(p00[r])) * wvv0
                  + fast_tanh(pqv1 + fast_tanh(q01[r]) + fast_tanh(p01[r])) * wvv1;
        vr[4 + r] = fast_tanh(pqv0 + fast_tanh(q10[r]) + fast_tanh(p10[r])) * wvv0
                  + fast_tanh(pqv1 + fast_tanh(q11[r]) + fast_tanh(p11[r])) * wvv1;
    }
    #pragma unroll
    for (int j = 0; j < 8; ++j) {
        float v = vr[j];
        v += __shfl_xor(v, 1);
        v += __shfl_xor(v, 2);
        v += __shfl_xor(v, 4);
        v += __shfl_xor(v, 8);
        if (lr == 0) e_part[(j >> 2) * 16 + lg * 4 + (j & 3)][w] = v;
    }
    __syncthreads();

    if (tid < 32) {
        int t = t0 + tid;
        if (t < T_SZ)
            energies[b * T_SZ + t] =
                (e_part[tid][0] + e_part[tid][1]) + (e_part[tid][2] + e_part[tid][3]);
    }
}

// ---------- kernel C: row softmax ----------
__global__ __launch_bounds__(256) void softmax_kernel(
    const float* __restrict__ energies, float* __restrict__ wout) {
    const int b = blockIdx.x, tid = threadIdx.x;
    const int lane = tid & 63, wv = tid >> 6;
    __shared__ float red[8];
    float ev[8];
    float m = -3.4e38f;
    #pragma unroll
    for (int i = 0; i < 8; ++i) {
        int idx = tid + i * 256;
        ev[i] = (idx < T_SZ) ? energies[b * T_SZ + idx] : -3.4e38f;
        m = fmaxf(m, ev[i]);
    }
    m = fmaxf(m, __shfl_xor(m, 1));  m = fmaxf(m, __shfl_xor(m, 2));
    m = fmaxf(m, __shfl_xor(m, 4));  m = fmaxf(m, __shfl_xor(m, 8));
    m = fmaxf(m, __shfl_xor(m, 16)); m = fmaxf(m, __shfl_xor(m, 32));
    if (lane == 0) red[wv] = m;
    __syncthreads();
    m = fmaxf(fmaxf(red[0], red[1]), fmaxf(red[2], red[3]));
    float p[8];
    float s = 0.0f;
    #pragma unroll
    for (int i = 0; i < 8; ++i) {
        int idx = tid + i * 256;
        p[i] = (idx < T_SZ) ? __expf(ev[i] - m) : 0.0f;
        s += p[i];
    }
    s += __shfl_xor(s, 1);  s += __shfl_xor(s, 2);
    s += __shfl_xor(s, 4);  s += __shfl_xor(s, 8);
    s += __shfl_xor(s, 16); s += __shfl_xor(s, 32);
    if (lane == 0) red[4 + wv] = s;
    __syncthreads();
    float Z = (red[4] + red[5]) + (red[6] + red[7]);
    float inv = 1.0f / Z;
    #pragma unroll
    for (int i = 0; i < 8; ++i) {
        int idx = tid + i * 256;
        if (idx < T_SZ) wout[b * T_SZ + idx] = p[i] * inv;
    }
}

// ---------- kernel D: partial contexts ----------
// grid (20, 64): chunk of 100 t's; thread owns float2 of m.
__global__ __launch_bounds__(256) void ctx_partial_kernel(
    const float* __restrict__ memory, const float* __restrict__ wts,
    float* __restrict__ part) {
    const int ci = blockIdx.x, b = blockIdx.y, tid = threadIdx.x;
    const float2* m2 = (const float2*)memory;
    float2 acc = {0.0f, 0.0f};
    const int t0 = ci * 100, t1 = t0 + 100;
    #pragma unroll 4
    for (int t = t0; t < t1; ++t) {
        float wgt = wts[b * T_SZ + t];
        float2 v = m2[((size_t)(b * T_SZ + t)) * 256 + tid];
        acc.x += wgt * v.x;
        acc.y += wgt * v.y;
    }
    ((float2*)part)[(b * 20 + ci) * 256 + tid] = acc;
}

// ---------- kernel E: reduce partials ----------
__global__ __launch_bounds__(256) void ctx_reduce_kernel(
    const float* __restrict__ part, float* __restrict__ ctx) {
    const int b = blockIdx.x, tid = threadIdx.x;
    const float2* p2 = (const float2*)part;
    float2 acc = {0.0f, 0.0f};
    #pragma unroll
    for (int ci = 0; ci < 20; ++ci) {
        float2 v = p2[(b * 20 + ci) * 256 + tid];
        acc.x += v.x;
        acc.y += v.y;
    }
    ((float2*)ctx)[b * 256 + tid] = acc;
}

// ---------- launch ----------
extern "C" void kernel_launch(void* const* d_in, const int* in_sizes, int n_in,
                              void* d_out, int out_size, void* d_ws, size_t ws_size,
                              hipStream_t stream) {
    const float* ahs    = (const float*)d_in[0];
    const float* memory = (const float*)d_in[1];
    const float* awcat  = (const float*)d_in[2];
    const float* Wq     = (const float*)d_in[3];
    const float* Wm     = (const float*)d_in[4];
    const float* Wv     = (const float*)d_in[5];
    const float* Wconv  = (const float*)d_in[6];
    const float* Wl     = (const float*)d_in[7];

    float* out = (float*)d_out;
    float* ctx = out;                 // [64][512]
    float* wts = out + B_SZ * MD;     // [64][2000]

    char* ws = (char*)d_ws;
    float* pq             = (float*)(ws);             // 32 KB
    unsigned short* WB    = (unsigned short*)(ws + 32768);   // 128 KB
    unsigned short* WL    = (unsigned short*)(ws + 163840);  // 8 KB
    float* energies       = (float*)(ws + 172032);    // 500 KB
    float* part           = (float*)(ws + 684032);    // 2.5 MB

    prep_kernel<<<97, 256, 0, stream>>>(ahs, Wq, Wm, Wl, pq, WB, WL);
    energy_kernel<<<dim3(63, 64), 256, 0, stream>>>(memory, awcat, Wconv, Wv,
                                                    pq, WB, WL, energies);
    softmax_kernel<<<64, 256, 0, stream>>>(energies, wts);
    ctx_partial_kernel<<<dim3(20, 64), 256, 0, stream>>>(memory, wts, part);
    ctx_reduce_kernel<<<64, 256, 0, stream>>>(part, ctx);
}

// Round 2
// 106.985 us; speedup vs baseline: 1.3902x; 1.3902x over previous
//
#include <hip/hip_runtime.h>

// ---------- types ----------
typedef __attribute__((ext_vector_type(8))) short s16x8;   // 8 x bf16 (4 VGPR)
typedef __attribute__((ext_vector_type(4))) float f32x4;   // MFMA acc

#define B_SZ 64
#define T_SZ 2000
#define QD 1024
#define MD 512
#define AD 128
#define NF 32
#define KW 31
#define NTILE 63

// ---------- helpers ----------
__device__ __forceinline__ unsigned short f2bf(float f) {
    unsigned int u = __float_as_uint(f);
    unsigned int r = (u + 0x7FFFu + ((u >> 16) & 1u)) >> 16;  // RNE
    return (unsigned short)r;
}
__device__ __forceinline__ unsigned int pack2bf(float a, float b) {
    return (unsigned int)f2bf(a) | ((unsigned int)f2bf(b) << 16);
}
__device__ __forceinline__ float fast_tanh(float x) {
    float ax = fabsf(x);
    float e = __expf(2.0f * ax);
    float r = 1.0f - 2.0f * __builtin_amdgcn_rcpf(e + 1.0f);
    return x < 0.0f ? -r : r;
}

// ---------- kernel A: pq + weight packing ----------
__global__ __launch_bounds__(256) void prep_kernel(
    const float* __restrict__ ahs, const float* __restrict__ Wq,
    const float* __restrict__ Wm, const float* __restrict__ Wl,
    float* __restrict__ pq, unsigned short* __restrict__ WB,
    unsigned short* __restrict__ WL) {
    const int blk = blockIdx.x, tid = threadIdx.x;
    if (blk < 64) {
        __shared__ float q_sm[QD];
        ((float4*)q_sm)[tid] = ((const float4*)(ahs + blk * QD))[tid];
        __syncthreads();
        if (tid < AD) {
            float acc = 0.0f;
            for (int k = 0; k < QD; ++k) acc += q_sm[k] * Wq[k * AD + tid];
            pq[blk * AD + tid] = fast_tanh(acc);
        }
    } else if (blk < 96) {
        int cidx = (blk - 64) * 256 + tid;        // 0..8191 = (n,s,l)
        int n = cidx >> 10, s = (cidx >> 6) & 15, l = cidx & 63;
        int col = n * 16 + (l & 15);
        int krow = s * 32 + (l >> 4) * 8;
        float v[8];
        #pragma unroll
        for (int j = 0; j < 8; ++j) v[j] = Wm[(krow + j) * AD + col];
        uint4 pk;
        pk.x = pack2bf(v[0], v[1]); pk.y = pack2bf(v[2], v[3]);
        pk.z = pack2bf(v[4], v[5]); pk.w = pack2bf(v[6], v[7]);
        *(uint4*)(WB + cidx * 8) = pk;
    } else {
        for (int h = 0; h < 2; ++h) {
            int cidx = h * 256 + tid;             // 0..511 = (n,l)
            int n = cidx >> 6, l = cidx & 63;
            int col = n * 16 + (l & 15);
            int krow = (l >> 4) * 8;
            float v[8];
            #pragma unroll
            for (int j = 0; j < 8; ++j) v[j] = Wl[(krow + j) * AD + col];
            uint4 pk;
            pk.x = pack2bf(v[0], v[1]); pk.y = pack2bf(v[2], v[3]);
            pk.z = pack2bf(v[4], v[5]); pk.w = pack2bf(v[6], v[7]);
            *(uint4*)(WL + cidx * 8) = pk;
        }
    }
}

// ---------- kernel B: fused conv + pm + ploc + energies + ctx partials ----------
// grid (63, 64); block 256 (4 waves). t-tile = 32.
__global__ __launch_bounds__(256) void energy_kernel(
    const float* __restrict__ memory, const float* __restrict__ awcat,
    const float* __restrict__ Wconv, const float* __restrict__ Wv,
    const float* __restrict__ pq, const unsigned short* __restrict__ WB,
    const unsigned short* __restrict__ WL, float* __restrict__ energies,
    float* __restrict__ ctile, float* __restrict__ mloc, int do_fuse) {
    const int tile = blockIdx.x;
    const int b = blockIdx.y;
    const int t0 = tile * 32;
    const int tid = threadIdx.x;

    __shared__ __align__(16) unsigned short Atile[32 * 512]; // bf16, XOR-swizzled
    __shared__ float aw_sm[2][64];
    __shared__ __align__(16) unsigned short conv_sm[32 * 40]; // row stride 40 bf16
    __shared__ float e_part[32][4];
    __shared__ float p_sm[32];

    // awc slice: indices i=0..62 -> t = t0-15+i  (zero pad OOB)
    if (tid < 128) {
        int c = tid >> 6, i = tid & 63;
        float v = 0.0f;
        int tv = t0 - 15 + i;
        if (i < 63 && tv >= 0 && tv < T_SZ) v = awcat[(b * 2 + c) * T_SZ + tv];
        aw_sm[c][i] = v;
    }

    // stage memory tile -> bf16 LDS, swizzled: byte ^= (row&7)<<4
    {
        const float4* msrc = (const float4*)(memory + ((size_t)b * T_SZ + t0) * MD);
        #pragma unroll
        for (int it = 0; it < 8; ++it) {
            int cid = it * 256 + tid;          // 2048 chunks of 8 floats
            int r = cid >> 6, cc = cid & 63;
            float4 v0 = {0, 0, 0, 0}, v1 = {0, 0, 0, 0};
            if (t0 + r < T_SZ) {
                v0 = msrc[r * 128 + cc * 2];
                v1 = msrc[r * 128 + cc * 2 + 1];
            }
            uint4 pk;
            pk.x = pack2bf(v0.x, v0.y); pk.y = pack2bf(v0.z, v0.w);
            pk.z = pack2bf(v1.x, v1.y); pk.w = pack2bf(v1.z, v1.w);
            int off = (r * 1024 + cc * 16) ^ ((r & 7) << 4);
            *(uint4*)((char*)Atile + off) = pk;
        }
    }
    __syncthreads();

    // conv1d: thread = (f = tid&31, tq = tid>>5); 4 t's per thread
    {
        int f = tid & 31, tq = tid >> 5;
        float acc[4] = {0, 0, 0, 0};
        for (int k = 0; k < KW; ++k) {
            #pragma unroll
            for (int c = 0; c < 2; ++c) {
                float wv = Wconv[(k * 2 + c) * NF + f];
                #pragma unroll
                for (int tt = 0; tt < 4; ++tt)
                    acc[tt] += wv * aw_sm[c][tq + tt * 8 + k];
            }
        }
        #pragma unroll
        for (int tt = 0; tt < 4; ++tt)
            conv_sm[(tq + tt * 8) * 40 + f] = f2bf(acc[tt]);
    }
    __syncthreads();

    // MFMA phase
    const int w = tid >> 6, l = tid & 63;
    const int lr = l & 15, lg = l >> 4;
    const int d0 = (2 * w + 0) * 16 + lr;
    const int d1 = (2 * w + 1) * 16 + lr;
    const float pqv0 = pq[b * AD + d0], pqv1 = pq[b * AD + d1];
    const float wvv0 = Wv[d0], wvv1 = Wv[d1];

    f32x4 zero4 = {0, 0, 0, 0};
    f32x4 p00 = zero4, p01 = zero4, p10 = zero4, p11 = zero4;

    const s16x8* wbp = (const s16x8*)WB;
    const int swz = (lr & 7) << 4;
    const int abase0 = lr * 1024 + lg * 16;          // mtile 0 row byte base
    const int abase1 = (16 + lr) * 1024 + lg * 16;   // mtile 1

    #pragma unroll
    for (int s = 0; s < 16; ++s) {
        s16x8 a0 = *(const s16x8*)((const char*)Atile + ((abase0 + s * 64) ^ swz));
        s16x8 a1 = *(const s16x8*)((const char*)Atile + ((abase1 + s * 64) ^ swz));
        s16x8 b0 = wbp[((2 * w + 0) * 16 + s) * 64 + l];
        s16x8 b1 = wbp[((2 * w + 1) * 16 + s) * 64 + l];
        p00 = __builtin_amdgcn_mfma_f32_16x16x32_bf16(a0, b0, p00, 0, 0, 0);
        p01 = __builtin_amdgcn_mfma_f32_16x16x32_bf16(a0, b1, p01, 0, 0, 0);
        p10 = __builtin_amdgcn_mfma_f32_16x16x32_bf16(a1, b0, p10, 0, 0, 0);
        p11 = __builtin_amdgcn_mfma_f32_16x16x32_bf16(a1, b1, p11, 0, 0, 0);
    }

    // ploc MFMA (K=32, one step)
    s16x8 la0 = *(const s16x8*)((const char*)conv_sm + (lr * 80 + lg * 16));
    s16x8 la1 = *(const s16x8*)((const char*)conv_sm + ((16 + lr) * 80 + lg * 16));
    const s16x8* wlp = (const s16x8*)WL;
    s16x8 lb0 = wlp[(2 * w + 0) * 64 + l];
    s16x8 lb1 = wlp[(2 * w + 1) * 64 + l];
    f32x4 q00 = __builtin_amdgcn_mfma_f32_16x16x32_bf16(la0, lb0, zero4, 0, 0, 0);
    f32x4 q01 = __builtin_amdgcn_mfma_f32_16x16x32_bf16(la0, lb1, zero4, 0, 0, 0);
    f32x4 q10 = __builtin_amdgcn_mfma_f32_16x16x32_bf16(la1, lb0, zero4, 0, 0, 0);
    f32x4 q11 = __builtin_amdgcn_mfma_f32_16x16x32_bf16(la1, lb1, zero4, 0, 0, 0);

    // epilogue: e[t] partial = sum_d tanh(pq + tanh(ploc) + tanh(pm)) * Wv
    float vr[8];
    #pragma unroll
    for (int r = 0; r < 4; ++r) {
        vr[r]     = fast_tanh(pqv0 + fast_tanh(q00[r]) + fast_tanh(p00[r])) * wvv0
                  + fast_tanh(pqv1 + fast_tanh(q01[r]) + fast_tanh(p01[r])) * wvv1;
        vr[4 + r] = fast_tanh(pqv0 + fast_tanh(q10[r]) + fast_tanh(p10[r])) * wvv0
                  + fast_tanh(pqv1 + fast_tanh(q11[r]) + fast_tanh(p11[r])) * wvv1;
    }
    #pragma unroll
    for (int j = 0; j < 8; ++j) {
        float v = vr[j];
        v += __shfl_xor(v, 1);
        v += __shfl_xor(v, 2);
        v += __shfl_xor(v, 4);
        v += __shfl_xor(v, 8);
        if (lr == 0) e_part[(j >> 2) * 16 + lg * 4 + (j & 3)][w] = v;
    }
    __syncthreads();

    if (tid < 32) {
        int t = t0 + tid;
        bool valid = t < T_SZ;
        float e = (e_part[tid][0] + e_part[tid][1]) + (e_part[tid][2] + e_part[tid][3]);
        if (valid) energies[b * T_SZ + t] = e;
        if (do_fuse) {
            // tile-local softmax numerators (lanes 0..31 of wave 0)
            float m = valid ? e : -3.4e38f;
            m = fmaxf(m, __shfl_xor(m, 1));
            m = fmaxf(m, __shfl_xor(m, 2));
            m = fmaxf(m, __shfl_xor(m, 4));
            m = fmaxf(m, __shfl_xor(m, 8));
            m = fmaxf(m, __shfl_xor(m, 16));
            p_sm[tid] = valid ? __expf(e - m) : 0.0f;
            if (tid == 0) mloc[b * NTILE + tile] = m;
        }
    }
    if (!do_fuse) return;
    __syncthreads();

    // ctx partial: thread owns d = 2*tid, 2*tid+1
    {
        float c0 = 0.0f, c1 = 0.0f;
        const int boff = tid * 4;
        #pragma unroll
        for (int t = 0; t < 32; ++t) {
            float p = p_sm[t];
            unsigned int pk = *(const unsigned int*)(
                (const char*)Atile + ((t * 1024 + boff) ^ ((t & 7) << 4)));
            c0 += p * __uint_as_float(pk << 16);
            c1 += p * __uint_as_float(pk & 0xffff0000u);
        }
        float2 o; o.x = c0; o.y = c1;
        ((float2*)ctile)[((b * NTILE + tile) << 8) + tid] = o;
    }
}

// ---------- kernel C: row softmax (+ global M, 1/Z) ----------
__global__ __launch_bounds__(256) void softmax_kernel(
    const float* __restrict__ energies, float* __restrict__ wout,
    float* __restrict__ Mb, float* __restrict__ invZb) {
    const int b = blockIdx.x, tid = threadIdx.x;
    const int lane = tid & 63, wv = tid >> 6;
    __shared__ float red[8];
    float ev[8];
    float m = -3.4e38f;
    #pragma unroll
    for (int i = 0; i < 8; ++i) {
        int idx = tid + i * 256;
        ev[i] = (idx < T_SZ) ? energies[b * T_SZ + idx] : -3.4e38f;
        m = fmaxf(m, ev[i]);
    }
    m = fmaxf(m, __shfl_xor(m, 1));  m = fmaxf(m, __shfl_xor(m, 2));
    m = fmaxf(m, __shfl_xor(m, 4));  m = fmaxf(m, __shfl_xor(m, 8));
    m = fmaxf(m, __shfl_xor(m, 16)); m = fmaxf(m, __shfl_xor(m, 32));
    if (lane == 0) red[wv] = m;
    __syncthreads();
    m = fmaxf(fmaxf(red[0], red[1]), fmaxf(red[2], red[3]));
    float p[8];
    float s = 0.0f;
    #pragma unroll
    for (int i = 0; i < 8; ++i) {
        int idx = tid + i * 256;
        p[i] = (idx < T_SZ) ? __expf(ev[i] - m) : 0.0f;
        s += p[i];
    }
    s += __shfl_xor(s, 1);  s += __shfl_xor(s, 2);
    s += __shfl_xor(s, 4);  s += __shfl_xor(s, 8);
    s += __shfl_xor(s, 16); s += __shfl_xor(s, 32);
    if (lane == 0) red[4 + wv] = s;
    __syncthreads();
    float Z = (red[4] + red[5]) + (red[6] + red[7]);
    float inv = 1.0f / Z;
    if (tid == 0) { Mb[b] = m; invZb[b] = inv; }
    #pragma unroll
    for (int i = 0; i < 8; ++i) {
        int idx = tid + i * 256;
        if (idx < T_SZ) wout[b * T_SZ + idx] = p[i] * inv;
    }
}

// ---------- kernel D: fused ctx reduce (8.25 MB read) ----------
__global__ __launch_bounds__(256) void ctx_reduce_fused_kernel(
    const float* __restrict__ ctile, const float* __restrict__ mloc,
    const float* __restrict__ Mb, const float* __restrict__ invZb,
    float* __restrict__ ctx) {
    const int b = blockIdx.x, tid = threadIdx.x;
    const float M = Mb[b], iZ = invZb[b];
    float2 acc = {0.0f, 0.0f};
    #pragma unroll 7
    for (int tl = 0; tl < NTILE; ++tl) {
        float sc = __expf(mloc[b * NTILE + tl] - M);
        float2 v = ((const float2*)ctile)[((b * NTILE + tl) << 8) + tid];
        acc.x += sc * v.x;
        acc.y += sc * v.y;
    }
    float2 o; o.x = acc.x * iZ; o.y = acc.y * iZ;
    ((float2*)ctx)[(b << 8) + tid] = o;
}

// ---------- fallback kernels (two-pass, used only if ws too small) ----------
__global__ __launch_bounds__(256) void ctx_partial_kernel(
    const float* __restrict__ memory, const float* __restrict__ wts,
    float* __restrict__ part) {
    const int ci = blockIdx.x, b = blockIdx.y, tid = threadIdx.x;
    const float2* m2 = (const float2*)memory;
    float2 acc = {0.0f, 0.0f};
    const int t0 = ci * 100, t1 = t0 + 100;
    #pragma unroll 4
    for (int t = t0; t < t1; ++t) {
        float wgt = wts[b * T_SZ + t];
        float2 v = m2[((size_t)(b * T_SZ + t)) * 256 + tid];
        acc.x += wgt * v.x;
        acc.y += wgt * v.y;
    }
    ((float2*)part)[(b * 20 + ci) * 256 + tid] = acc;
}

__global__ __launch_bounds__(256) void ctx_reduce_kernel(
    const float* __restrict__ part, float* __restrict__ ctx) {
    const int b = blockIdx.x, tid = threadIdx.x;
    const float2* p2 = (const float2*)part;
    float2 acc = {0.0f, 0.0f};
    #pragma unroll
    for (int ci = 0; ci < 20; ++ci) {
        float2 v = p2[(b * 20 + ci) * 256 + tid];
        acc.x += v.x;
        acc.y += v.y;
    }
    ((float2*)ctx)[b * 256 + tid] = acc;
}

// ---------- launch ----------
extern "C" void kernel_launch(void* const* d_in, const int* in_sizes, int n_in,
                              void* d_out, int out_size, void* d_ws, size_t ws_size,
                              hipStream_t stream) {
    const float* ahs    = (const float*)d_in[0];
    const float* memory = (const float*)d_in[1];
    const float* awcat  = (const float*)d_in[2];
    const float* Wq     = (const float*)d_in[3];
    const float* Wm     = (const float*)d_in[4];
    const float* Wv     = (const float*)d_in[5];
    const float* Wconv  = (const float*)d_in[6];
    const float* Wl     = (const float*)d_in[7];

    float* out = (float*)d_out;
    float* ctx = out;                 // [64][512]
    float* wts = out + B_SZ * MD;     // [64][2000]

    char* ws = (char*)d_ws;
    float* pq             = (float*)(ws);                    // 32 KB
    unsigned short* WB    = (unsigned short*)(ws + 32768);   // 128 KB
    unsigned short* WL    = (unsigned short*)(ws + 163840);  // 8 KB
    float* energies       = (float*)(ws + 172032);           // 512 KB
    float* mloc           = (float*)(ws + 684032);           // 16.1 KB
    float* Mb             = (float*)(ws + 700416);           // 256 B
    float* invZb          = (float*)(ws + 700672);           // 256 B
    float* ctile          = (float*)(ws + 701440);           // 8.25 MB
    float* part           = (float*)(ws + 701440);           // fallback 2.5 MB

    const size_t need_fused = 701440 + (size_t)B_SZ * NTILE * MD * 4;
    const int do_fuse = (ws_size >= need_fused) ? 1 : 0;

    prep_kernel<<<97, 256, 0, stream>>>(ahs, Wq, Wm, Wl, pq, WB, WL);
    energy_kernel<<<dim3(NTILE, 64), 256, 0, stream>>>(
        memory, awcat, Wconv, Wv, pq, WB, WL, energies, ctile, mloc, do_fuse);
    softmax_kernel<<<64, 256, 0, stream>>>(energies, wts, Mb, invZb);
    if (do_fuse) {
        ctx_reduce_fused_kernel<<<64, 256, 0, stream>>>(ctile, mloc, Mb, invZb, ctx);
    } else {
        ctx_partial_kernel<<<dim3(20, 64), 256, 0, stream>>>(memory, wts, part);
        ctx_reduce_kernel<<<64, 256, 0, stream>>>(part, ctx);
    }
}

// Round 3
// 96.670 us; speedup vs baseline: 1.5386x; 1.1067x over previous
//
#include <hip/hip_runtime.h>
#include <hip/hip_bf16.h>

// ---------- types ----------
typedef __attribute__((ext_vector_type(8))) short s16x8;   // 8 x bf16 (4 VGPR)
typedef __attribute__((ext_vector_type(4))) float f32x4;   // MFMA acc

#define B_SZ 64
#define T_SZ 2000
#define QD 1024
#define MD 512
#define AD 128
#define NF 32
#define KW 31
#define NTILE 63
#define ASTRIDE 1056   // Atile row stride in BYTES (264 words == 8 mod 32 banks)

// ---------- helpers ----------
__device__ __forceinline__ unsigned short f2bf(float f) {
    unsigned int u = __float_as_uint(f);
    unsigned int r = (u + 0x7FFFu + ((u >> 16) & 1u)) >> 16;  // RNE
    return (unsigned short)r;
}
__device__ __forceinline__ unsigned int pack2bf_manual(float a, float b) {
    return (unsigned int)f2bf(a) | ((unsigned int)f2bf(b) << 16);
}
// HW packed convert (compiler emits v_cvt_pk_bf16_f32); used for staging + WB
__device__ __forceinline__ unsigned int pack2bf(float a, float b) {
    union { __hip_bfloat162 h; unsigned int u; } cv;
    cv.h = __float22bfloat162_rn(float2{a, b});
    return cv.u;
}
__device__ __forceinline__ float fast_tanh(float x) {
    float ax = fabsf(x);
    float e = __expf(2.0f * ax);
    float r = 1.0f - 2.0f * __builtin_amdgcn_rcpf(e + 1.0f);
    return x < 0.0f ? -r : r;
}

// ---------- kernel A: pq + weight packing ----------
__global__ __launch_bounds__(256) void prep_kernel(
    const float* __restrict__ ahs, const float* __restrict__ Wq,
    const float* __restrict__ Wm, const float* __restrict__ Wl,
    float* __restrict__ pq, unsigned short* __restrict__ WB,
    unsigned short* __restrict__ WL) {
    const int blk = blockIdx.x, tid = threadIdx.x;
    if (blk < 64) {
        __shared__ float q_sm[QD];
        __shared__ float part[AD];
        ((float4*)q_sm)[tid] = ((const float4*)(ahs + blk * QD))[tid];
        __syncthreads();
        const int d = tid & 127, kh = tid >> 7;
        const int k0 = kh * 512;
        float a0 = 0, a1 = 0, a2 = 0, a3 = 0;
        for (int k = k0; k < k0 + 512; k += 4) {
            a0 += q_sm[k]     * Wq[(k)     * AD + d];
            a1 += q_sm[k + 1] * Wq[(k + 1) * AD + d];
            a2 += q_sm[k + 2] * Wq[(k + 2) * AD + d];
            a3 += q_sm[k + 3] * Wq[(k + 3) * AD + d];
        }
        float s = (a0 + a1) + (a2 + a3);
        if (kh) part[d] = s;
        __syncthreads();
        if (tid < AD) pq[blk * AD + tid] = fast_tanh(s + part[tid]);
    } else if (blk < 96) {
        int cidx = (blk - 64) * 256 + tid;        // 0..8191 = (n,s,l)
        int n = cidx >> 10, s = (cidx >> 6) & 15, l = cidx & 63;
        int col = n * 16 + (l & 15);
        int krow = s * 32 + (l >> 4) * 8;
        float v[8];
        #pragma unroll
        for (int j = 0; j < 8; ++j) v[j] = Wm[(krow + j) * AD + col];
        uint4 pk;
        pk.x = pack2bf(v[0], v[1]); pk.y = pack2bf(v[2], v[3]);
        pk.z = pack2bf(v[4], v[5]); pk.w = pack2bf(v[6], v[7]);
        *(uint4*)(WB + cidx * 8) = pk;
    } else {
        for (int h = 0; h < 2; ++h) {
            int cidx = h * 256 + tid;             // 0..511 = (n,l)
            int n = cidx >> 6, l = cidx & 63;
            int col = n * 16 + (l & 15);
            int krow = (l >> 4) * 8;
            float v[8];
            #pragma unroll
            for (int j = 0; j < 8; ++j) v[j] = Wl[(krow + j) * AD + col];
            // manual pack to stay bit-consistent with conv_sm's manual f2bf
            uint4 pk;
            pk.x = pack2bf_manual(v[0], v[1]); pk.y = pack2bf_manual(v[2], v[3]);
            pk.z = pack2bf_manual(v[4], v[5]); pk.w = pack2bf_manual(v[6], v[7]);
            *(uint4*)(WL + cidx * 8) = pk;
        }
    }
}

// ---------- kernel B: fused conv + pm + ploc + energies + ctx partials ----------
// grid (63, 64); block 256 (4 waves). t-tile = 32.
__global__ __launch_bounds__(256) void energy_kernel(
    const float* __restrict__ memory, const float* __restrict__ awcat,
    const float* __restrict__ Wconv, const float* __restrict__ Wv,
    const float* __restrict__ pq, const unsigned short* __restrict__ WB,
    const unsigned short* __restrict__ WL, float* __restrict__ energies,
    float* __restrict__ ctile, float* __restrict__ mloc, int do_fuse) {
    const int tile = blockIdx.x;
    const int b = blockIdx.y;
    const int t0 = tile * 32;
    const int tid = threadIdx.x;

    __shared__ __align__(16) unsigned short Atile[32 * (ASTRIDE / 2)]; // bf16, swizzled
    __shared__ float aw_sm[2][64];
    __shared__ __align__(16) unsigned short conv_sm[32 * 40]; // row stride 40 bf16
    __shared__ float e_part[32][4];
    __shared__ float p_sm[32];

    // awc slice: indices i=0..62 -> t = t0-15+i  (zero pad OOB)
    if (tid < 128) {
        int c = tid >> 6, i = tid & 63;
        float v = 0.0f;
        int tv = t0 - 15 + i;
        if (i < 63 && tv >= 0 && tv < T_SZ) v = awcat[(b * 2 + c) * T_SZ + tv];
        aw_sm[c][i] = v;
    }

    // stage memory tile -> bf16 LDS; in-row XOR swizzle: j ^= (r&7)<<4
    {
        const float4* msrc = (const float4*)(memory + ((size_t)b * T_SZ + t0) * MD);
        #pragma unroll
        for (int it = 0; it < 8; ++it) {
            int cid = it * 256 + tid;          // 2048 chunks of 8 floats
            int r = cid >> 6, cc = cid & 63;
            float4 v0 = {0, 0, 0, 0}, v1 = {0, 0, 0, 0};
            if (t0 + r < T_SZ) {
                v0 = msrc[r * 128 + cc * 2];
                v1 = msrc[r * 128 + cc * 2 + 1];
            }
            uint4 pk;
            pk.x = pack2bf(v0.x, v0.y); pk.y = pack2bf(v0.z, v0.w);
            pk.z = pack2bf(v1.x, v1.y); pk.w = pack2bf(v1.z, v1.w);
            int off = r * ASTRIDE + ((cc * 16) ^ ((r & 7) << 4));
            *(uint4*)((char*)Atile + off) = pk;
        }
    }
    __syncthreads();

    // conv1d: thread = (f = tid&31, tq = tid>>5); 4 t's per thread
    {
        int f = tid & 31, tq = tid >> 5;
        float acc[4] = {0, 0, 0, 0};
        for (int k = 0; k < KW; ++k) {
            #pragma unroll
            for (int c = 0; c < 2; ++c) {
                float wv = Wconv[(k * 2 + c) * NF + f];
                #pragma unroll
                for (int tt = 0; tt < 4; ++tt)
                    acc[tt] += wv * aw_sm[c][tq + tt * 8 + k];
            }
        }
        #pragma unroll
        for (int tt = 0; tt < 4; ++tt)
            conv_sm[(tq + tt * 8) * 40 + f] = f2bf(acc[tt]);
    }
    __syncthreads();

    // MFMA phase
    const int w = tid >> 6, l = tid & 63;
    const int lr = l & 15, lg = l >> 4;
    const int d0 = (2 * w + 0) * 16 + lr;
    const int d1 = (2 * w + 1) * 16 + lr;
    const float pqv0 = pq[b * AD + d0], pqv1 = pq[b * AD + d1];
    const float wvv0 = Wv[d0], wvv1 = Wv[d1];

    f32x4 zero4 = {0, 0, 0, 0};
    f32x4 p00 = zero4, p01 = zero4, p10 = zero4, p11 = zero4;

    const s16x8* wbp = (const s16x8*)WB;
    const int swz = (lr & 7) << 4;
    const int rbase0 = lr * ASTRIDE;          // mtile 0 row byte base
    const int rbase1 = (16 + lr) * ASTRIDE;   // mtile 1
    const int inb = lg * 16;

    #pragma unroll
    for (int s = 0; s < 16; ++s) {
        int j = (inb + s * 64) ^ swz;
        s16x8 a0 = *(const s16x8*)((const char*)Atile + rbase0 + j);
        s16x8 a1 = *(const s16x8*)((const char*)Atile + rbase1 + j);
        s16x8 b0 = wbp[((2 * w + 0) * 16 + s) * 64 + l];
        s16x8 b1 = wbp[((2 * w + 1) * 16 + s) * 64 + l];
        p00 = __builtin_amdgcn_mfma_f32_16x16x32_bf16(a0, b0, p00, 0, 0, 0);
        p01 = __builtin_amdgcn_mfma_f32_16x16x32_bf16(a0, b1, p01, 0, 0, 0);
        p10 = __builtin_amdgcn_mfma_f32_16x16x32_bf16(a1, b0, p10, 0, 0, 0);
        p11 = __builtin_amdgcn_mfma_f32_16x16x32_bf16(a1, b1, p11, 0, 0, 0);
    }

    // ploc MFMA (K=32, one step)
    s16x8 la0 = *(const s16x8*)((const char*)conv_sm + (lr * 80 + lg * 16));
    s16x8 la1 = *(const s16x8*)((const char*)conv_sm + ((16 + lr) * 80 + lg * 16));
    const s16x8* wlp = (const s16x8*)WL;
    s16x8 lb0 = wlp[(2 * w + 0) * 64 + l];
    s16x8 lb1 = wlp[(2 * w + 1) * 64 + l];
    f32x4 q00 = __builtin_amdgcn_mfma_f32_16x16x32_bf16(la0, lb0, zero4, 0, 0, 0);
    f32x4 q01 = __builtin_amdgcn_mfma_f32_16x16x32_bf16(la0, lb1, zero4, 0, 0, 0);
    f32x4 q10 = __builtin_amdgcn_mfma_f32_16x16x32_bf16(la1, lb0, zero4, 0, 0, 0);
    f32x4 q11 = __builtin_amdgcn_mfma_f32_16x16x32_bf16(la1, lb1, zero4, 0, 0, 0);

    // epilogue: e[t] partial = sum_d tanh(pq + tanh(ploc) + tanh(pm)) * Wv
    float vr[8];
    #pragma unroll
    for (int r = 0; r < 4; ++r) {
        vr[r]     = fast_tanh(pqv0 + fast_tanh(q00[r]) + fast_tanh(p00[r])) * wvv0
                  + fast_tanh(pqv1 + fast_tanh(q01[r]) + fast_tanh(p01[r])) * wvv1;
        vr[4 + r] = fast_tanh(pqv0 + fast_tanh(q10[r]) + fast_tanh(p10[r])) * wvv0
                  + fast_tanh(pqv1 + fast_tanh(q11[r]) + fast_tanh(p11[r])) * wvv1;
    }
    #pragma unroll
    for (int j = 0; j < 8; ++j) {
        float v = vr[j];
        v += __shfl_xor(v, 1);
        v += __shfl_xor(v, 2);
        v += __shfl_xor(v, 4);
        v += __shfl_xor(v, 8);
        if (lr == 0) e_part[(j >> 2) * 16 + lg * 4 + (j & 3)][w] = v;
    }
    __syncthreads();

    if (tid < 32) {
        int t = t0 + tid;
        bool valid = t < T_SZ;
        float e = (e_part[tid][0] + e_part[tid][1]) + (e_part[tid][2] + e_part[tid][3]);
        if (valid) energies[b * T_SZ + t] = e;
        if (do_fuse) {
            float m = valid ? e : -3.4e38f;
            m = fmaxf(m, __shfl_xor(m, 1));
            m = fmaxf(m, __shfl_xor(m, 2));
            m = fmaxf(m, __shfl_xor(m, 4));
            m = fmaxf(m, __shfl_xor(m, 8));
            m = fmaxf(m, __shfl_xor(m, 16));
            p_sm[tid] = valid ? __expf(e - m) : 0.0f;
            if (tid == 0) mloc[b * NTILE + tile] = m;
        }
    }
    if (!do_fuse) return;
    __syncthreads();

    // ctx partial: thread owns d = 2*tid, 2*tid+1
    {
        float c0 = 0.0f, c1 = 0.0f;
        const int boff = tid * 4;
        #pragma unroll
        for (int t = 0; t < 32; ++t) {
            float p = p_sm[t];
            unsigned int pk = *(const unsigned int*)(
                (const char*)Atile + t * ASTRIDE + (boff ^ ((t & 7) << 4)));
            c0 += p * __uint_as_float(pk << 16);
            c1 += p * __uint_as_float(pk & 0xffff0000u);
        }
        float2 o; o.x = c0; o.y = c1;
        ((float2*)ctile)[((b * NTILE + tile) << 8) + tid] = o;
    }
}

// ---------- kernel C (fused path): softmax + ctx reduce ----------
__global__ __launch_bounds__(256) void softmax_ctx_kernel(
    const float* __restrict__ energies, const float* __restrict__ mloc,
    const float* __restrict__ ctile, float* __restrict__ wout,
    float* __restrict__ ctx) {
    const int b = blockIdx.x, tid = threadIdx.x;
    const int lane = tid & 63, wv = tid >> 6;
    __shared__ float red[8];
    __shared__ float sc_sm[NTILE];
    float ev[8];
    float m = -3.4e38f;
    #pragma unroll
    for (int i = 0; i < 8; ++i) {
        int idx = tid + i * 256;
        ev[i] = (idx < T_SZ) ? energies[b * T_SZ + idx] : -3.4e38f;
        m = fmaxf(m, ev[i]);
    }
    m = fmaxf(m, __shfl_xor(m, 1));  m = fmaxf(m, __shfl_xor(m, 2));
    m = fmaxf(m, __shfl_xor(m, 4));  m = fmaxf(m, __shfl_xor(m, 8));
    m = fmaxf(m, __shfl_xor(m, 16)); m = fmaxf(m, __shfl_xor(m, 32));
    if (lane == 0) red[wv] = m;
    __syncthreads();
    m = fmaxf(fmaxf(red[0], red[1]), fmaxf(red[2], red[3]));
    float p[8];
    float s = 0.0f;
    #pragma unroll
    for (int i = 0; i < 8; ++i) {
        int idx = tid + i * 256;
        p[i] = (idx < T_SZ) ? __expf(ev[i] - m) : 0.0f;
        s += p[i];
    }
    s += __shfl_xor(s, 1);  s += __shfl_xor(s, 2);
    s += __shfl_xor(s, 4);  s += __shfl_xor(s, 8);
    s += __shfl_xor(s, 16); s += __shfl_xor(s, 32);
    if (lane == 0) red[4 + wv] = s;
    __syncthreads();
    float Z = (red[4] + red[5]) + (red[6] + red[7]);
    float inv = 1.0f / Z;
    #pragma unroll
    for (int i = 0; i < 8; ++i) {
        int idx = tid + i * 256;
        if (idx < T_SZ) wout[b * T_SZ + idx] = p[i] * inv;
    }
    if (tid < NTILE) sc_sm[tid] = __expf(mloc[b * NTILE + tid] - m) * inv;
    __syncthreads();

    float2 acc = {0.0f, 0.0f};
    #pragma unroll 7
    for (int tl = 0; tl < NTILE; ++tl) {
        float sc = sc_sm[tl];
        float2 v = ((const float2*)ctile)[((b * NTILE + tl) << 8) + tid];
        acc.x += sc * v.x;
        acc.y += sc * v.y;
    }
    ((float2*)ctx)[(b << 8) + tid] = acc;
}

// ---------- fallback kernels (two-pass, used only if ws too small) ----------
__global__ __launch_bounds__(256) void softmax_kernel(
    const float* __restrict__ energies, float* __restrict__ wout) {
    const int b = blockIdx.x, tid = threadIdx.x;
    const int lane = tid & 63, wv = tid >> 6;
    __shared__ float red[8];
    float ev[8];
    float m = -3.4e38f;
    #pragma unroll
    for (int i = 0; i < 8; ++i) {
        int idx = tid + i * 256;
        ev[i] = (idx < T_SZ) ? energies[b * T_SZ + idx] : -3.4e38f;
        m = fmaxf(m, ev[i]);
    }
    m = fmaxf(m, __shfl_xor(m, 1));  m = fmaxf(m, __shfl_xor(m, 2));
    m = fmaxf(m, __shfl_xor(m, 4));  m = fmaxf(m, __shfl_xor(m, 8));
    m = fmaxf(m, __shfl_xor(m, 16)); m = fmaxf(m, __shfl_xor(m, 32));
    if (lane == 0) red[wv] = m;
    __syncthreads();
    m = fmaxf(fmaxf(red[0], red[1]), fmaxf(red[2], red[3]));
    float p[8];
    float s = 0.0f;
    #pragma unroll
    for (int i = 0; i < 8; ++i) {
        int idx = tid + i * 256;
        p[i] = (idx < T_SZ) ? __expf(ev[i] - m) : 0.0f;
        s += p[i];
    }
    s += __shfl_xor(s, 1);  s += __shfl_xor(s, 2);
    s += __shfl_xor(s, 4);  s += __shfl_xor(s, 8);
    s += __shfl_xor(s, 16); s += __shfl_xor(s, 32);
    if (lane == 0) red[4 + wv] = s;
    __syncthreads();
    float Z = (red[4] + red[5]) + (red[6] + red[7]);
    float inv = 1.0f / Z;
    #pragma unroll
    for (int i = 0; i < 8; ++i) {
        int idx = tid + i * 256;
        if (idx < T_SZ) wout[b * T_SZ + idx] = p[i] * inv;
    }
}

__global__ __launch_bounds__(256) void ctx_partial_kernel(
    const float* __restrict__ memory, const float* __restrict__ wts,
    float* __restrict__ part) {
    const int ci = blockIdx.x, b = blockIdx.y, tid = threadIdx.x;
    const float2* m2 = (const float2*)memory;
    float2 acc = {0.0f, 0.0f};
    const int t0 = ci * 100, t1 = t0 + 100;
    #pragma unroll 4
    for (int t = t0; t < t1; ++t) {
        float wgt = wts[b * T_SZ + t];
        float2 v = m2[((size_t)(b * T_SZ + t)) * 256 + tid];
        acc.x += wgt * v.x;
        acc.y += wgt * v.y;
    }
    ((float2*)part)[(b * 20 + ci) * 256 + tid] = acc;
}

__global__ __launch_bounds__(256) void ctx_reduce_kernel(
    const float* __restrict__ part, float* __restrict__ ctx) {
    const int b = blockIdx.x, tid = threadIdx.x;
    const float2* p2 = (const float2*)part;
    float2 acc = {0.0f, 0.0f};
    #pragma unroll
    for (int ci = 0; ci < 20; ++ci) {
        float2 v = p2[(b * 20 + ci) * 256 + tid];
        acc.x += v.x;
        acc.y += v.y;
    }
    ((float2*)ctx)[b * 256 + tid] = acc;
}

// ---------- launch ----------
extern "C" void kernel_launch(void* const* d_in, const int* in_sizes, int n_in,
                              void* d_out, int out_size, void* d_ws, size_t ws_size,
                              hipStream_t stream) {
    const float* ahs    = (const float*)d_in[0];
    const float* memory = (const float*)d_in[1];
    const float* awcat  = (const float*)d_in[2];
    const float* Wq     = (const float*)d_in[3];
    const float* Wm     = (const float*)d_in[4];
    const float* Wv     = (const float*)d_in[5];
    const float* Wconv  = (const float*)d_in[6];
    const float* Wl     = (const float*)d_in[7];

    float* out = (float*)d_out;
    float* ctx = out;                 // [64][512]
    float* wts = out + B_SZ * MD;     // [64][2000]

    char* ws = (char*)d_ws;
    float* pq             = (float*)(ws);                    // 32 KB
    unsigned short* WB    = (unsigned short*)(ws + 32768);   // 128 KB
    unsigned short* WL    = (unsigned short*)(ws + 163840);  // 8 KB
    float* energies       = (float*)(ws + 172032);           // 512 KB
    float* mloc           = (float*)(ws + 684032);           // 16.1 KB
    float* ctile          = (float*)(ws + 701440);           // 8.25 MB
    float* part           = (float*)(ws + 701440);           // fallback 2.5 MB

    const size_t need_fused = 701440 + (size_t)B_SZ * NTILE * MD * 4;
    const int do_fuse = (ws_size >= need_fused) ? 1 : 0;

    prep_kernel<<<97, 256, 0, stream>>>(ahs, Wq, Wm, Wl, pq, WB, WL);
    energy_kernel<<<dim3(NTILE, 64), 256, 0, stream>>>(
        memory, awcat, Wconv, Wv, pq, WB, WL, energies, ctile, mloc, do_fuse);
    if (do_fuse) {
        softmax_ctx_kernel<<<64, 256, 0, stream>>>(energies, mloc, ctile, wts, ctx);
    } else {
        softmax_kernel<<<64, 256, 0, stream>>>(energies, wts);
        ctx_partial_kernel<<<dim3(20, 64), 256, 0, stream>>>(memory, wts, part);
        ctx_reduce_kernel<<<64, 256, 0, stream>>>(part, ctx);
    }
}